// Round 8
// baseline (78.321 us; speedup 1.0000x reference)
//
#include <hip/hip_runtime.h>
#include <stdint.h>

typedef _Float16 f16x8 __attribute__((ext_vector_type(8)));
typedef float f32x4 __attribute__((ext_vector_type(4)));

__device__ __forceinline__ uint32_t pack2(float a, float b) {
    union { _Float16 h[2]; uint32_t u; } p;
    p.h[0] = (_Float16)a; p.h[1] = (_Float16)b;
    return p.u;
}

__device__ __forceinline__ uint16_t key16(float v) {
    _Float16 hx = (_Float16)fmaxf(v, 0.0f);
    return __builtin_bit_cast(uint16_t, hx);
}

__device__ __forceinline__ f32x4 MF(f16x8 a, f16x8 b, f32x4 c) {
    return __builtin_amdgcn_mfma_f32_16x16x32_f16(a, b, c, 0, 0, 0);
}

__global__ __launch_bounds__(512, 2)
void gfc_main(const float* __restrict__ X, const float* __restrict__ gp,
              float* __restrict__ out) {
    // 64 KB: 4 f-slices x (64 c-rows x 256 B = 128 t f16), swizzled
    __shared__ __align__(16) unsigned char XS[65536];
    __shared__ float Rbuf[4][64];

    // XCD swizzle: 4 sibling f-quads of one (n, 16-f line group) share an XCD
    int j = blockIdx.x;
    int xcd = j & 7, s = j >> 3;
    int gi = s >> 2, fq4 = s & 3;
    int g = gi * 8 + xcd;
    int n = g >> 2, f16g = g & 3;
    int f0 = f16g * 16 + fq4 * 4;

    int tid = threadIdx.x;
    int wid = tid >> 6, lane = tid & 63;
    int w4 = wid & 3, hi = wid >> 2;     // f within quad; row-half of C
    int l4 = lane & 15, lg = lane >> 4;

    float p10 = exp2f(gp[0] * 3.3219280948873623f);   // 10^gammad
    const float* Xn = X + (size_t)n * 1048576 + f0;

    f32x4 dd[2][4];
    #pragma unroll
    for (int a = 0; a < 2; ++a)
        #pragma unroll
        for (int b = 0; b < 4; ++b) dd[a][b] = f32x4{0, 0, 0, 0};

    float4 pv[8][2];   // one 128-t chunk in flight: 64 VGPRs

    auto load_chunk = [&](int t0) {   // 16 float4 loads, all in flight
        #pragma unroll
        for (int k = 0; k < 8; ++k) {
            int c = k * 8 + wid;
            const float* p = Xn + (size_t)c * 16384 + t0 * 64 + lane * 128;
            pv[k][0] = *(const float4*)p;         // t = t0 + 2*lane
            pv[k][1] = *(const float4*)(p + 64);  // t = t0 + 2*lane+1
        }
    };
    auto write_chunk = [&]() {
        #pragma unroll
        for (int k = 0; k < 8; ++k) {
            int c = k * 8 + wid;
            int o = c * 256 + ((lane * 4) ^ ((c & 7) << 4));
            *(uint32_t*)(XS + o)         = pack2(pv[k][0].x, pv[k][1].x);
            *(uint32_t*)(XS + 16384 + o) = pack2(pv[k][0].y, pv[k][1].y);
            *(uint32_t*)(XS + 32768 + o) = pack2(pv[k][0].z, pv[k][1].z);
            *(uint32_t*)(XS + 49152 + o) = pack2(pv[k][0].w, pv[k][1].w);
        }
    };
    auto gram_buf = [&]() {
        const unsigned char* bp = XS + w4 * 16384;
        #pragma unroll
        for (int ks = 0; ks < 4; ++ks) {
            f16x8 fr[4];
            #pragma unroll
            for (int i2 = 0; i2 < 4; ++i2)
                fr[i2] = *(const f16x8*)(bp + (i2 * 16 + l4) * 256 +
                                         ((ks * 64 + lg * 16) ^ ((l4 & 7) << 4)));
            if (!hi) {
                #pragma unroll
                for (int tj = 0; tj < 4; ++tj) {
                    dd[0][tj] = MF(fr[tj], fr[0], dd[0][tj]);
                    dd[1][tj] = MF(fr[tj], fr[1], dd[1][tj]);
                }
            } else {
                #pragma unroll
                for (int tj = 0; tj < 4; ++tj) {
                    dd[0][tj] = MF(fr[tj], fr[2], dd[0][tj]);
                    dd[1][tj] = MF(fr[tj], fr[3], dd[1][tj]);
                }
            }
        }
    };

    // ---- pipeline: chunk0 stage; chunk1 loads fly under gram0 ----
    load_chunk(0);
    write_chunk();            // vmcnt drain (prologue, unavoidable)
    load_chunk(128);          // chunk1 in flight across gram0
    __syncthreads();          // B1: buf ready

    gram_buf();               // chunk0
    __syncthreads();          // B2: chunk0 reads done

    write_chunk();            // chunk1 (loads mostly landed under gram0)
    __syncthreads();          // B3: buf ready

    gram_buf();               // chunk1

    // ---- R = diag(G). Diag tiles: dd[0][2hi], dd[1][2hi+1]; lg*4+reg==l4 ----
    {
        f32x4 dg0 = hi ? dd[0][2] : dd[0][0];
        f32x4 dg1 = hi ? dd[1][3] : dd[1][1];
        if (lg == (l4 >> 2)) {
            int r = l4 & 3;
            float v0 = r == 0 ? dg0[0] : r == 1 ? dg0[1] : r == 2 ? dg0[2] : dg0[3];
            float v1 = r == 0 ? dg1[0] : r == 1 ? dg1[1] : r == 2 ? dg1[2] : dg1[3];
            Rbuf[w4][(hi * 2) * 16 + l4] = v0;
            Rbuf[w4][(hi * 2 + 1) * 16 + l4] = v1;
        }
    }
    __syncthreads();   // B4: Rbuf ready; XS reusable

    // ---- D = R_row + R_col - 2G in place; 32 keys packed into 16 u32 ----
    float Rr0 = Rbuf[w4][(hi * 2) * 16 + l4];
    float Rr1 = Rbuf[w4][(hi * 2 + 1) * 16 + l4];
    #pragma unroll
    for (int tj = 0; tj < 4; ++tj) {
        f32x4 Rc = *(const f32x4*)&Rbuf[w4][tj * 16 + lg * 4];
        #pragma unroll
        for (int r = 0; r < 4; ++r) {
            dd[0][tj][r] = Rr0 + Rc[r] - 2.0f * dd[0][tj][r];
            dd[1][tj][r] = Rr1 + Rc[r] - 2.0f * dd[1][tj][r];
        }
    }

    uint32_t pk[32];   // [0:16) mine, [16:32) partner's
    #pragma unroll
    for (int tt = 0; tt < 2; ++tt) {
        int row = (hi * 2 + tt) * 16 + l4;
        #pragma unroll
        for (int tj = 0; tj < 4; ++tj)
            #pragma unroll
            for (int rp = 0; rp < 2; ++rp) {
                int col0 = tj * 16 + lg * 4 + 2 * rp;
                uint32_t k0 = (row < col0)     ? key16(dd[tt][tj][2 * rp])     : 0x7FFFu;
                uint32_t k1 = (row < col0 + 1) ? key16(dd[tt][tj][2 * rp + 1]) : 0x7FFFu;
                pk[tt * 8 + tj * 2 + rp] = k0 | (k1 << 16);
            }
    }

    // ---- one-shot packed-key exchange between the wave pair ----
    {
        uint32_t* base = (uint32_t*)(XS + w4 * 16384);
        uint32_t* mywr = base + hi * 1024;
        #pragma unroll
        for (int e = 0; e < 16; ++e) mywr[e * 64 + lane] = pk[e];
        __syncthreads();   // B5
        const uint32_t* prd = base + (hi ^ 1) * 1024;
        #pragma unroll
        for (int e = 0; e < 16; ++e) pk[16 + e] = prd[e * 64 + lane];
    }

    // ---- exact rank-1008 select on 15-bit f16 keys ----
    int u = 0;
    for (int bit = 14; bit >= 0; --bit) {
        uint32_t cand = (uint32_t)(u | (1 << bit));
        int cnt = 0;
        #pragma unroll
        for (int i = 0; i < 32; ++i) {
            cnt += ((pk[i] & 0xFFFFu) < cand) ? 1 : 0;
            cnt += ((pk[i] >> 16) < cand) ? 1 : 0;
        }
        #pragma unroll
        for (int off = 32; off; off >>= 1) cnt += __shfl_xor(cnt, off, 64);
        if (cnt <= 1008) u |= (1 << bit);
    }
    float sigma2 = (float)__builtin_bit_cast(_Float16, (uint16_t)u);
    float ninv = -1.0f / (2.0f * p10 * sigma2);

    // ---- epilogue: A = exp(-D/denom); float4 stores (4 consecutive cols) ----
    float* op = out + ((size_t)(n * 64 + f0 + w4) << 12);
    #pragma unroll
    for (int tt = 0; tt < 2; ++tt) {
        int row = (hi * 2 + tt) * 16 + l4;
        #pragma unroll
        for (int tj = 0; tj < 4; ++tj) {
            float4 rv;
            rv.x = __expf(dd[tt][tj][0] * ninv);
            rv.y = __expf(dd[tt][tj][1] * ninv);
            rv.z = __expf(dd[tt][tj][2] * ninv);
            rv.w = __expf(dd[tt][tj][3] * ninv);
            *(float4*)(op + row * 64 + tj * 16 + lg * 4) = rv;
        }
    }
}

extern "C" void kernel_launch(void* const* d_in, const int* in_sizes, int n_in,
                              void* d_out, int out_size, void* d_ws, size_t ws_size,
                              hipStream_t stream) {
    (void)in_sizes; (void)n_in; (void)out_size; (void)d_ws; (void)ws_size;
    const float* X  = (const float*)d_in[0];
    const float* gp = (const float*)d_in[1];
    float* out = (float*)d_out;
    gfc_main<<<512, 512, 0, stream>>>(X, gp, out);
}

// Round 9
// 76.557 us; speedup vs baseline: 1.0230x; 1.0230x over previous
//
#include <hip/hip_runtime.h>
#include <stdint.h>

typedef _Float16 f16x8 __attribute__((ext_vector_type(8)));
typedef float f32x4 __attribute__((ext_vector_type(4)));

__device__ __forceinline__ f32x4 MF(f16x8 a, f16x8 b, f32x4 c) {
    return __builtin_amdgcn_mfma_f32_16x16x32_f16(a, b, c, 0, 0, 0);
}

__device__ __forceinline__ uint16_t h16(float v) {
    _Float16 h = (_Float16)v;
    return __builtin_bit_cast(uint16_t, h);
}

__device__ __forceinline__ uint16_t key16(float v) {
    _Float16 hx = (_Float16)fmaxf(v, 0.0f);
    return __builtin_bit_cast(uint16_t, hx);
}

__device__ __forceinline__ uint32_t pack2(float a, float b) {
    return (uint32_t)h16(a) | ((uint32_t)h16(b) << 16);
}

// ============ Kernel A: X (n,c,t,f) f32 -> W[n][f][c][t] f16 ============
// Block = (n, c). Coalesced full-line reads; LDS [t][f] transpose; coalesced
// 16B stores. W row (f,c) = 256 t * 2B = 512 B contiguous.
__global__ __launch_bounds__(256)
void gfc_prep(const float* __restrict__ X, uint16_t* __restrict__ W) {
    __shared__ uint16_t T[256 * 66];   // [t][f], row = 66 halfwords (132 B pad)
    int n = blockIdx.x >> 6, c = blockIdx.x & 63;
    int tid = threadIdx.x;
    const float* src = X + ((size_t)n * 64 + c) * 16384;

    #pragma unroll
    for (int rb = 0; rb < 2; ++rb) {
        float4 v[8];
        #pragma unroll
        for (int i = 0; i < 8; ++i) {
            int o = (rb * 8 + i) * 256 + tid;       // o = t*16 + fj
            v[i] = *(const float4*)(src + (size_t)o * 4);
        }
        #pragma unroll
        for (int i = 0; i < 8; ++i) {
            int o = (rb * 8 + i) * 256 + tid;
            int t = o >> 4, fj = o & 15;
            uint16_t* row = &T[t * 66 + fj * 4];
            row[0] = h16(v[i].x);
            row[1] = h16(v[i].y);
            row[2] = h16(v[i].z);
            row[3] = h16(v[i].w);
        }
    }
    __syncthreads();

    int f = tid >> 2, q = tid & 3;     // thread owns (f, 64-t quarter)
    uint16_t* dst = W + (((size_t)n * 64 + f) * 64 + c) * 256 + q * 64;
    #pragma unroll
    for (int jj = 0; jj < 8; ++jj) {
        uint32_t w[4];
        #pragma unroll
        for (int p = 0; p < 4; ++p) {
            int t = q * 64 + jj * 8 + p * 2;
            uint32_t lo = T[t * 66 + f];
            uint32_t hi = T[(t + 1) * 66 + f];
            w[p] = lo | (hi << 16);
        }
        *(uint4*)(dst + jj * 8) = *(uint4*)w;
    }
}

// ============ Kernel B: gram from W (direct global frags) + median + exp ====
__global__ __launch_bounds__(512, 2)
void gfc_main2(const uint16_t* __restrict__ W, const float* __restrict__ gp,
               float* __restrict__ out) {
    __shared__ float Rbuf[4][64];
    __shared__ uint32_t EX[8][1024];   // packed-key exchange, 4 KB per wave

    // XCD swizzle: all 16 f-quad blocks of one n-group share an XCD L2
    int j = blockIdx.x;
    int xcd = j & 7, r = j >> 3;
    int fq = r & 15, nh = r >> 4;
    int n = xcd * 4 + nh;
    int f0 = fq * 4;

    int tid = threadIdx.x;
    int wid = tid >> 6, lane = tid & 63;
    int w4 = wid & 3, hi = wid >> 2;     // f within quad; row-half of C
    int l4 = lane & 15, lg = lane >> 4;

    float p10 = exp2f(gp[0] * 3.3219280948873623f);   // 10^gammad
    const uint16_t* Wf = W + ((size_t)n * 64 + f0 + w4) * 16384;

    f32x4 dd[2][4];
    #pragma unroll
    for (int a = 0; a < 2; ++a)
        #pragma unroll
        for (int b = 0; b < 4; ++b) dd[a][b] = f32x4{0, 0, 0, 0};

    // Gram: frags straight from global W (coalesced 16 full lines / instr).
    // fr[i2] = Wf16[c = i2*16+l4][t = ks*32 + lg*8 .. +7]  (r8-verified map)
    #pragma unroll
    for (int ks = 0; ks < 8; ++ks) {
        f16x8 fr[4];
        #pragma unroll
        for (int i2 = 0; i2 < 4; ++i2)
            fr[i2] = *(const f16x8*)(Wf + (i2 * 16 + l4) * 256 + ks * 32 + lg * 8);
        if (!hi) {
            #pragma unroll
            for (int tj = 0; tj < 4; ++tj) {
                dd[0][tj] = MF(fr[tj], fr[0], dd[0][tj]);
                dd[1][tj] = MF(fr[tj], fr[1], dd[1][tj]);
            }
        } else {
            #pragma unroll
            for (int tj = 0; tj < 4; ++tj) {
                dd[0][tj] = MF(fr[tj], fr[2], dd[0][tj]);
                dd[1][tj] = MF(fr[tj], fr[3], dd[1][tj]);
            }
        }
    }

    // R = diag(G). Diag tiles: dd[0][2hi], dd[1][2hi+1]; elem where lg*4+reg==l4
    {
        f32x4 dg0 = hi ? dd[0][2] : dd[0][0];
        f32x4 dg1 = hi ? dd[1][3] : dd[1][1];
        if (lg == (l4 >> 2)) {
            int rr = l4 & 3;
            float v0 = rr == 0 ? dg0[0] : rr == 1 ? dg0[1] : rr == 2 ? dg0[2] : dg0[3];
            float v1 = rr == 0 ? dg1[0] : rr == 1 ? dg1[1] : rr == 2 ? dg1[2] : dg1[3];
            Rbuf[w4][(hi * 2) * 16 + l4] = v0;
            Rbuf[w4][(hi * 2 + 1) * 16 + l4] = v1;
        }
    }
    __syncthreads();   // B1: Rbuf ready

    // D = R_row + R_col - 2G in place; 32 keys packed into 16 u32
    float Rr0 = Rbuf[w4][(hi * 2) * 16 + l4];
    float Rr1 = Rbuf[w4][(hi * 2 + 1) * 16 + l4];
    #pragma unroll
    for (int tj = 0; tj < 4; ++tj) {
        f32x4 Rc = *(const f32x4*)&Rbuf[w4][tj * 16 + lg * 4];
        #pragma unroll
        for (int rr = 0; rr < 4; ++rr) {
            dd[0][tj][rr] = Rr0 + Rc[rr] - 2.0f * dd[0][tj][rr];
            dd[1][tj][rr] = Rr1 + Rc[rr] - 2.0f * dd[1][tj][rr];
        }
    }

    uint32_t pk[32];   // [0:16) mine, [16:32) partner's
    #pragma unroll
    for (int tt = 0; tt < 2; ++tt) {
        int row = (hi * 2 + tt) * 16 + l4;
        #pragma unroll
        for (int tj = 0; tj < 4; ++tj)
            #pragma unroll
            for (int rp = 0; rp < 2; ++rp) {
                int col0 = tj * 16 + lg * 4 + 2 * rp;
                uint32_t k0 = (row < col0)     ? key16(dd[tt][tj][2 * rp])     : 0x7FFFu;
                uint32_t k1 = (row < col0 + 1) ? key16(dd[tt][tj][2 * rp + 1]) : 0x7FFFu;
                pk[tt * 8 + tj * 2 + rp] = k0 | (k1 << 16);
            }
    }

    // one-shot packed-key exchange between the wave pair (wid <-> wid^4)
    {
        uint32_t* mywr = EX[wid];
        #pragma unroll
        for (int e = 0; e < 16; ++e) mywr[e * 64 + lane] = pk[e];
        __syncthreads();   // B2
        const uint32_t* prd = EX[wid ^ 4];
        #pragma unroll
        for (int e = 0; e < 16; ++e) pk[16 + e] = prd[e * 64 + lane];
    }

    // exact rank-1008 select on 15-bit f16 keys
    int u = 0;
    for (int bit = 14; bit >= 0; --bit) {
        uint32_t cand = (uint32_t)(u | (1 << bit));
        int cnt = 0;
        #pragma unroll
        for (int i = 0; i < 32; ++i) {
            cnt += ((pk[i] & 0xFFFFu) < cand) ? 1 : 0;
            cnt += ((pk[i] >> 16) < cand) ? 1 : 0;
        }
        #pragma unroll
        for (int off = 32; off; off >>= 1) cnt += __shfl_xor(cnt, off, 64);
        if (cnt <= 1008) u |= (1 << bit);
    }
    float sigma2 = (float)__builtin_bit_cast(_Float16, (uint16_t)u);
    float ninv = -1.0f / (2.0f * p10 * sigma2);

    // epilogue: A = exp(-D/denom); float4 stores (4 consecutive cols)
    float* op = out + ((size_t)(n * 64 + f0 + w4) << 12);
    #pragma unroll
    for (int tt = 0; tt < 2; ++tt) {
        int row = (hi * 2 + tt) * 16 + l4;
        #pragma unroll
        for (int tj = 0; tj < 4; ++tj) {
            float4 rv;
            rv.x = __expf(dd[tt][tj][0] * ninv);
            rv.y = __expf(dd[tt][tj][1] * ninv);
            rv.z = __expf(dd[tt][tj][2] * ninv);
            rv.w = __expf(dd[tt][tj][3] * ninv);
            *(float4*)(op + row * 64 + tj * 16 + lg * 4) = rv;
        }
    }
}

// ============ Fallback (r8, proven): used only if ws < 64 MiB ============
__global__ __launch_bounds__(512, 2)
void gfc_fb(const float* __restrict__ X, const float* __restrict__ gp,
            float* __restrict__ out) {
    __shared__ __align__(16) unsigned char XS[65536];
    __shared__ float Rbuf[4][64];
    int j = blockIdx.x;
    int xcd = j & 7, s = j >> 3;
    int gi = s >> 2, fq4 = s & 3;
    int g = gi * 8 + xcd;
    int n = g >> 2, f16g = g & 3;
    int f0 = f16g * 16 + fq4 * 4;
    int tid = threadIdx.x;
    int wid = tid >> 6, lane = tid & 63;
    int w4 = wid & 3, hi = wid >> 2;
    int l4 = lane & 15, lg = lane >> 4;
    float p10 = exp2f(gp[0] * 3.3219280948873623f);
    const float* Xn = X + (size_t)n * 1048576 + f0;
    f32x4 dd[2][4];
    #pragma unroll
    for (int a = 0; a < 2; ++a)
        #pragma unroll
        for (int b = 0; b < 4; ++b) dd[a][b] = f32x4{0, 0, 0, 0};
    float4 pv[8][2];
    auto load_chunk = [&](int t0) {
        #pragma unroll
        for (int k = 0; k < 8; ++k) {
            int c = k * 8 + wid;
            const float* p = Xn + (size_t)c * 16384 + t0 * 64 + lane * 128;
            pv[k][0] = *(const float4*)p;
            pv[k][1] = *(const float4*)(p + 64);
        }
    };
    auto write_chunk = [&]() {
        #pragma unroll
        for (int k = 0; k < 8; ++k) {
            int c = k * 8 + wid;
            int o = c * 256 + ((lane * 4) ^ ((c & 7) << 4));
            *(uint32_t*)(XS + o)         = pack2(pv[k][0].x, pv[k][1].x);
            *(uint32_t*)(XS + 16384 + o) = pack2(pv[k][0].y, pv[k][1].y);
            *(uint32_t*)(XS + 32768 + o) = pack2(pv[k][0].z, pv[k][1].z);
            *(uint32_t*)(XS + 49152 + o) = pack2(pv[k][0].w, pv[k][1].w);
        }
    };
    auto gram_buf = [&]() {
        const unsigned char* bp = XS + w4 * 16384;
        #pragma unroll
        for (int ks = 0; ks < 4; ++ks) {
            f16x8 fr[4];
            #pragma unroll
            for (int i2 = 0; i2 < 4; ++i2)
                fr[i2] = *(const f16x8*)(bp + (i2 * 16 + l4) * 256 +
                                         ((ks * 64 + lg * 16) ^ ((l4 & 7) << 4)));
            if (!hi) {
                #pragma unroll
                for (int tj = 0; tj < 4; ++tj) {
                    dd[0][tj] = MF(fr[tj], fr[0], dd[0][tj]);
                    dd[1][tj] = MF(fr[tj], fr[1], dd[1][tj]);
                }
            } else {
                #pragma unroll
                for (int tj = 0; tj < 4; ++tj) {
                    dd[0][tj] = MF(fr[tj], fr[2], dd[0][tj]);
                    dd[1][tj] = MF(fr[tj], fr[3], dd[1][tj]);
                }
            }
        }
    };
    load_chunk(0);
    write_chunk();
    load_chunk(128);
    __syncthreads();
    gram_buf();
    __syncthreads();
    write_chunk();
    __syncthreads();
    gram_buf();
    {
        f32x4 dg0 = hi ? dd[0][2] : dd[0][0];
        f32x4 dg1 = hi ? dd[1][3] : dd[1][1];
        if (lg == (l4 >> 2)) {
            int rr = l4 & 3;
            float v0 = rr == 0 ? dg0[0] : rr == 1 ? dg0[1] : rr == 2 ? dg0[2] : dg0[3];
            float v1 = rr == 0 ? dg1[0] : rr == 1 ? dg1[1] : rr == 2 ? dg1[2] : dg1[3];
            Rbuf[w4][(hi * 2) * 16 + l4] = v0;
            Rbuf[w4][(hi * 2 + 1) * 16 + l4] = v1;
        }
    }
    __syncthreads();
    float Rr0 = Rbuf[w4][(hi * 2) * 16 + l4];
    float Rr1 = Rbuf[w4][(hi * 2 + 1) * 16 + l4];
    #pragma unroll
    for (int tj = 0; tj < 4; ++tj) {
        f32x4 Rc = *(const f32x4*)&Rbuf[w4][tj * 16 + lg * 4];
        #pragma unroll
        for (int rr = 0; rr < 4; ++rr) {
            dd[0][tj][rr] = Rr0 + Rc[rr] - 2.0f * dd[0][tj][rr];
            dd[1][tj][rr] = Rr1 + Rc[rr] - 2.0f * dd[1][tj][rr];
        }
    }
    uint32_t pk[32];
    #pragma unroll
    for (int tt = 0; tt < 2; ++tt) {
        int row = (hi * 2 + tt) * 16 + l4;
        #pragma unroll
        for (int tj = 0; tj < 4; ++tj)
            #pragma unroll
            for (int rp = 0; rp < 2; ++rp) {
                int col0 = tj * 16 + lg * 4 + 2 * rp;
                uint32_t k0 = (row < col0)     ? key16(dd[tt][tj][2 * rp])     : 0x7FFFu;
                uint32_t k1 = (row < col0 + 1) ? key16(dd[tt][tj][2 * rp + 1]) : 0x7FFFu;
                pk[tt * 8 + tj * 2 + rp] = k0 | (k1 << 16);
            }
    }
    {
        uint32_t* base = (uint32_t*)(XS + w4 * 16384);
        uint32_t* mywr = base + hi * 1024;
        #pragma unroll
        for (int e = 0; e < 16; ++e) mywr[e * 64 + lane] = pk[e];
        __syncthreads();
        const uint32_t* prd = base + (hi ^ 1) * 1024;
        #pragma unroll
        for (int e = 0; e < 16; ++e) pk[16 + e] = prd[e * 64 + lane];
    }
    int u = 0;
    for (int bit = 14; bit >= 0; --bit) {
        uint32_t cand = (uint32_t)(u | (1 << bit));
        int cnt = 0;
        #pragma unroll
        for (int i = 0; i < 32; ++i) {
            cnt += ((pk[i] & 0xFFFFu) < cand) ? 1 : 0;
            cnt += ((pk[i] >> 16) < cand) ? 1 : 0;
        }
        #pragma unroll
        for (int off = 32; off; off >>= 1) cnt += __shfl_xor(cnt, off, 64);
        if (cnt <= 1008) u |= (1 << bit);
    }
    float sigma2 = (float)__builtin_bit_cast(_Float16, (uint16_t)u);
    float ninv = -1.0f / (2.0f * p10 * sigma2);
    float* op = out + ((size_t)(n * 64 + f0 + w4) << 12);
    #pragma unroll
    for (int tt = 0; tt < 2; ++tt) {
        int row = (hi * 2 + tt) * 16 + l4;
        #pragma unroll
        for (int tj = 0; tj < 4; ++tj) {
            float4 rv;
            rv.x = __expf(dd[tt][tj][0] * ninv);
            rv.y = __expf(dd[tt][tj][1] * ninv);
            rv.z = __expf(dd[tt][tj][2] * ninv);
            rv.w = __expf(dd[tt][tj][3] * ninv);
            *(float4*)(op + row * 64 + tj * 16 + lg * 4) = rv;
        }
    }
}

extern "C" void kernel_launch(void* const* d_in, const int* in_sizes, int n_in,
                              void* d_out, int out_size, void* d_ws, size_t ws_size,
                              hipStream_t stream) {
    (void)in_sizes; (void)n_in; (void)out_size;
    const float* X  = (const float*)d_in[0];
    const float* gp = (const float*)d_in[1];
    float* outp = (float*)d_out;
    if (ws_size >= (size_t)67108864) {
        uint16_t* W = (uint16_t*)d_ws;
        gfc_prep<<<2048, 256, 0, stream>>>(X, W);
        gfc_main2<<<512, 512, 0, stream>>>(W, gp, outp);
    } else {
        gfc_fb<<<512, 512, 0, stream>>>(X, gp, outp);
    }
}

// Round 10
// 67.885 us; speedup vs baseline: 1.1537x; 1.1277x over previous
//
#include <hip/hip_runtime.h>
#include <stdint.h>

typedef _Float16 f16x8 __attribute__((ext_vector_type(8)));
typedef float f32x4 __attribute__((ext_vector_type(4)));

__device__ __forceinline__ f32x4 MF(f16x8 a, f16x8 b, f32x4 c) {
    return __builtin_amdgcn_mfma_f32_16x16x32_f16(a, b, c, 0, 0, 0);
}

__device__ __forceinline__ uint16_t key16(float v) {
    _Float16 hx = (_Float16)fmaxf(v, 0.0f);
    return __builtin_bit_cast(uint16_t, hx);
}

#if defined(__has_builtin)
# if __has_builtin(__builtin_amdgcn_global_load_lds)
#  define HAVE_GLDS 1
# endif
#endif
#ifndef HAVE_GLDS
# define HAVE_GLDS 0
#endif

__global__ __launch_bounds__(512, 2)
void gfc_main(const float* __restrict__ X, const float* __restrict__ gp,
              float* __restrict__ out) {
    // Two 32 KB chunk buffers. Chunk = 32 t of all 64 c for the 4 f's:
    // row c = 32 granules x 16 B; granule tt holds f32 X[n][c][T0+tt][f0..f0+3],
    // stored at slot (tt ^ (c&15)) -- swizzle applied on the GLOBAL source so
    // the DMA dest stays linear (base + lane*16).
    __shared__ __align__(16) unsigned char XS[65536];
    __shared__ float Rbuf[4][64];

    // XCD swizzle: 4 sibling f-quads of one (n, 16-f line group) share an XCD
    int j = blockIdx.x;
    int xcd = j & 7, s = j >> 3;
    int gi = s >> 2, fq4 = s & 3;
    int g = gi * 8 + xcd;
    int n = g >> 2, f16g = g & 3;
    int f0 = f16g * 16 + fq4 * 4;

    int tid = threadIdx.x;
    int wid = tid >> 6, lane = tid & 63;
    int w4 = wid & 3, hi = wid >> 2;     // f within quad; row-half of C
    int l4 = lane & 15, lg = lane >> 4;
    int pos = lane & 31, cs = lane >> 5; // staging: granule slot, row-sub

    float p10 = exp2f(gp[0] * 3.3219280948873623f);   // 10^gammad
    const unsigned char* Xb = (const unsigned char*)(X + (size_t)n * 1048576 + f0);

    f32x4 dd[2][4];
    #pragma unroll
    for (int a = 0; a < 2; ++a)
        #pragma unroll
        for (int b = 0; b < 4; ++b) dd[a][b] = f32x4{0, 0, 0, 0};

    // issue one chunk's DMA: 4 instrs/wave, each = 2 c-rows (64 lanes x 16 B)
    auto stage = [&](int bsel, int T0) {
        unsigned char* bb = XS + bsel * 32768;
        #pragma unroll
        for (int i = 0; i < 4; ++i) {
            int c0 = wid * 8 + i * 2;
            int c  = c0 + cs;
            int tt = pos ^ (c & 15);
            const unsigned char* gsrc = Xb + (size_t)c * 65536 + (size_t)(T0 + tt) * 256;
#if HAVE_GLDS
            __builtin_amdgcn_global_load_lds(
                (const uint32_t __attribute__((address_space(1)))*)(uintptr_t)gsrc,
                (uint32_t __attribute__((address_space(3)))*)(uintptr_t)(bb + c0 * 512),
                16, 0, 0);
#else
            *(uint4*)(bb + c0 * 512 + lane * 16) = *(const uint4*)gsrc;
#endif
        }
    };

    // gram over one 32-t chunk: frags from swizzled f32 granules + f16 cast
    auto gram = [&](int bsel) {
        const float* B = (const float*)(XS + bsel * 32768);
        f16x8 fr[4];
        #pragma unroll
        for (int i2 = 0; i2 < 4; ++i2) {
            int c = i2 * 16 + l4;          // c & 15 == l4
            int base = c * 128 + w4;       // dword index
            float v[8];
            #pragma unroll
            for (int jj = 0; jj < 8; ++jj) {
                int tl = lg * 8 + jj;
                v[jj] = B[base + (((tl ^ l4)) << 2)];
            }
            f16x8 f;
            #pragma unroll
            for (int jj = 0; jj < 8; ++jj) f[jj] = (_Float16)v[jj];
            fr[i2] = f;
        }
        if (!hi) {
            #pragma unroll
            for (int tj = 0; tj < 4; ++tj) {
                dd[0][tj] = MF(fr[tj], fr[0], dd[0][tj]);
                dd[1][tj] = MF(fr[tj], fr[1], dd[1][tj]);
            }
        } else {
            #pragma unroll
            for (int tj = 0; tj < 4; ++tj) {
                dd[0][tj] = MF(fr[tj], fr[2], dd[0][tj]);
                dd[1][tj] = MF(fr[tj], fr[3], dd[1][tj]);
            }
        }
    };

    // ---- DMA pipeline: 8 chunks of 32 t, dbuf, one barrier per chunk ----
    stage(0, 0);
    __syncthreads();                 // drain chunk0
    #pragma unroll
    for (int k = 0; k < 8; ++k) {
        if (k < 7) stage((k + 1) & 1, (k + 1) * 32);   // in flight across gram
        gram(k & 1);
        if (k < 7) __syncthreads();  // drains chunk k+1 DMA; buffers swap-safe
    }

    // ---- R = diag(G). Diag tiles: dd[0][2hi], dd[1][2hi+1]; lg*4+reg==l4 ----
    {
        f32x4 dg0 = hi ? dd[0][2] : dd[0][0];
        f32x4 dg1 = hi ? dd[1][3] : dd[1][1];
        if (lg == (l4 >> 2)) {
            int r = l4 & 3;
            float v0 = r == 0 ? dg0[0] : r == 1 ? dg0[1] : r == 2 ? dg0[2] : dg0[3];
            float v1 = r == 0 ? dg1[0] : r == 1 ? dg1[1] : r == 2 ? dg1[2] : dg1[3];
            Rbuf[w4][(hi * 2) * 16 + l4] = v0;
            Rbuf[w4][(hi * 2 + 1) * 16 + l4] = v1;
        }
    }
    __syncthreads();   // Rbuf ready; all XS gram reads done (XS reusable)

    // ---- D = R_row + R_col - 2G in place; 32 keys packed into 16 u32 ----
    float Rr0 = Rbuf[w4][(hi * 2) * 16 + l4];
    float Rr1 = Rbuf[w4][(hi * 2 + 1) * 16 + l4];
    #pragma unroll
    for (int tj = 0; tj < 4; ++tj) {
        f32x4 Rc = *(const f32x4*)&Rbuf[w4][tj * 16 + lg * 4];
        #pragma unroll
        for (int r = 0; r < 4; ++r) {
            dd[0][tj][r] = Rr0 + Rc[r] - 2.0f * dd[0][tj][r];
            dd[1][tj][r] = Rr1 + Rc[r] - 2.0f * dd[1][tj][r];
        }
    }

    uint32_t pk[32];   // [0:16) mine, [16:32) partner's
    #pragma unroll
    for (int tt = 0; tt < 2; ++tt) {
        int row = (hi * 2 + tt) * 16 + l4;
        #pragma unroll
        for (int tj = 0; tj < 4; ++tj)
            #pragma unroll
            for (int rp = 0; rp < 2; ++rp) {
                int col0 = tj * 16 + lg * 4 + 2 * rp;
                uint32_t k0 = (row < col0)     ? key16(dd[tt][tj][2 * rp])     : 0x7FFFu;
                uint32_t k1 = (row < col0 + 1) ? key16(dd[tt][tj][2 * rp + 1]) : 0x7FFFu;
                pk[tt * 8 + tj * 2 + rp] = k0 | (k1 << 16);
            }
    }

    // ---- one-shot packed-key exchange between the wave pair (reuses XS) ----
    {
        uint32_t* base = (uint32_t*)(XS + w4 * 8192);
        uint32_t* mywr = base + hi * 1024;
        #pragma unroll
        for (int e = 0; e < 16; ++e) mywr[e * 64 + lane] = pk[e];
        __syncthreads();
        const uint32_t* prd = base + (hi ^ 1) * 1024;
        #pragma unroll
        for (int e = 0; e < 16; ++e) pk[16 + e] = prd[e * 64 + lane];
    }

    // ---- exact rank-1008 select on 15-bit f16 keys (redundant per wave) ----
    int u = 0;
    for (int bit = 14; bit >= 0; --bit) {
        uint32_t cand = (uint32_t)(u | (1 << bit));
        int cnt = 0;
        #pragma unroll
        for (int i = 0; i < 32; ++i) {
            cnt += ((pk[i] & 0xFFFFu) < cand) ? 1 : 0;
            cnt += ((pk[i] >> 16) < cand) ? 1 : 0;
        }
        #pragma unroll
        for (int off = 32; off; off >>= 1) cnt += __shfl_xor(cnt, off, 64);
        if (cnt <= 1008) u |= (1 << bit);
    }
    float sigma2 = (float)__builtin_bit_cast(_Float16, (uint16_t)u);
    float ninv = -1.0f / (2.0f * p10 * sigma2);

    // ---- epilogue: A = exp(-D/denom); float4 stores (4 consecutive cols) ----
    float* op = out + ((size_t)(n * 64 + f0 + w4) << 12);
    #pragma unroll
    for (int tt = 0; tt < 2; ++tt) {
        int row = (hi * 2 + tt) * 16 + l4;
        #pragma unroll
        for (int tj = 0; tj < 4; ++tj) {
            float4 rv;
            rv.x = __expf(dd[tt][tj][0] * ninv);
            rv.y = __expf(dd[tt][tj][1] * ninv);
            rv.z = __expf(dd[tt][tj][2] * ninv);
            rv.w = __expf(dd[tt][tj][3] * ninv);
            *(float4*)(op + row * 64 + tj * 16 + lg * 4) = rv;
        }
    }
}

extern "C" void kernel_launch(void* const* d_in, const int* in_sizes, int n_in,
                              void* d_out, int out_size, void* d_ws, size_t ws_size,
                              hipStream_t stream) {
    (void)in_sizes; (void)n_in; (void)out_size; (void)d_ws; (void)ws_size;
    const float* X  = (const float*)d_in[0];
    const float* gp = (const float*)d_in[1];
    float* out = (float*)d_out;
    gfc_main<<<512, 512, 0, stream>>>(X, gp, out);
}